// Round 2
// baseline (1219.404 us; speedup 1.0000x reference)
//
#include <hip/hip_runtime.h>
#include <stdint.h>

typedef __bf16  bf16x8 __attribute__((ext_vector_type(8)));
typedef float   f32x4  __attribute__((ext_vector_type(4)));
typedef unsigned short u16;

#define TEMP 5.0f

// ---------- helpers ----------
__device__ inline float wsum(float v){
  #pragma unroll
  for (int off=32; off; off>>=1) v += __shfl_xor(v, off, 64);
  return v;
}
__device__ inline float wmax(float v){
  #pragma unroll
  for (int off=32; off; off>>=1) v = fmaxf(v, __shfl_xor(v, off, 64));
  return v;
}
__device__ inline u16 f2bf(float f){               // RNE float->bf16
  unsigned u = __float_as_uint(f);
  u = u + 0x7fffu + ((u>>16)&1u);
  return (u16)(u>>16);
}
__device__ inline float bfl(unsigned u){ return __uint_as_float(u<<16); }
__device__ inline float bfh(unsigned u){ return __uint_as_float(u & 0xffff0000u); }

// ---- cross-quad (lane ^16, ^32) reductions.
// gfx950 v_permlane16/32_swap: pure VALU, no LDS round-trip / lgkm wait.
#if __has_builtin(__builtin_amdgcn_permlane16_swap) && __has_builtin(__builtin_amdgcn_permlane32_swap)
__device__ inline int qsum_i(int c){
  auto a = __builtin_amdgcn_permlane16_swap((unsigned)c, (unsigned)c, false, false);
  c = (int)a[0] + (int)a[1];
  auto b = __builtin_amdgcn_permlane32_swap((unsigned)c, (unsigned)c, false, false);
  return (int)b[0] + (int)b[1];
}
__device__ inline float qsum_f(float v){
  auto a = __builtin_amdgcn_permlane16_swap(__float_as_uint(v), __float_as_uint(v), false, false);
  v = __uint_as_float(a[0]) + __uint_as_float(a[1]);
  auto b = __builtin_amdgcn_permlane32_swap(__float_as_uint(v), __float_as_uint(v), false, false);
  return __uint_as_float(b[0]) + __uint_as_float(b[1]);
}
__device__ inline float qmin_f(float v){
  auto a = __builtin_amdgcn_permlane16_swap(__float_as_uint(v), __float_as_uint(v), false, false);
  v = fminf(__uint_as_float(a[0]), __uint_as_float(a[1]));
  auto b = __builtin_amdgcn_permlane32_swap(__float_as_uint(v), __float_as_uint(v), false, false);
  return fminf(__uint_as_float(b[0]), __uint_as_float(b[1]));
}
__device__ inline float qmax_f(float v){
  auto a = __builtin_amdgcn_permlane16_swap(__float_as_uint(v), __float_as_uint(v), false, false);
  v = fmaxf(__uint_as_float(a[0]), __uint_as_float(a[1]));
  auto b = __builtin_amdgcn_permlane32_swap(__float_as_uint(v), __float_as_uint(v), false, false);
  return fmaxf(__uint_as_float(b[0]), __uint_as_float(b[1]));
}
#else
__device__ inline int qsum_i(int c){
  c += __shfl_xor(c, 16, 64); c += __shfl_xor(c, 32, 64); return c;
}
__device__ inline float qsum_f(float v){
  v += __shfl_xor(v, 16, 64); v += __shfl_xor(v, 32, 64); return v;
}
__device__ inline float qmin_f(float v){
  v = fminf(v, __shfl_xor(v, 16, 64)); v = fminf(v, __shfl_xor(v, 32, 64)); return v;
}
__device__ inline float qmax_f(float v){
  v = fmaxf(v, __shfl_xor(v, 16, 64)); v = fmaxf(v, __shfl_xor(v, 32, 64)); return v;
}
#endif

// async 16B global->LDS: lds dst is WAVE-UNIFORM base, HW adds lane*16
__device__ inline void cp16(void* lds_uniform, const void* g){
  __builtin_amdgcn_global_load_lds(
    (const __attribute__((address_space(1))) unsigned int*)g,
    (__attribute__((address_space(3))) unsigned int*)lds_uniform, 16, 0, 0);
}

// ---------- K0: normalize image features (32x512) ----------
__global__ void k_img(const float* __restrict__ X, float* __restrict__ imgn){
  int b = blockIdx.x, lane = threadIdx.x;
  const float* src = X + (size_t)b*512 + lane*8;
  float4 a = *(const float4*)src;
  float4 c = *(const float4*)(src+4);
  float ss = a.x*a.x+a.y*a.y+a.z*a.z+a.w*a.w + c.x*c.x+c.y*c.y+c.z*c.z+c.w*c.w;
  ss = wsum(ss);
  float inv = 1.0f/sqrtf(ss);
  float* dst = imgn + (size_t)b*512 + lane*8;
  float4 o0 = {a.x*inv,a.y*inv,a.z*inv,a.w*inv};
  float4 o1 = {c.x*inv,c.y*inv,c.z*inv,c.w*inv};
  *(float4*)dst = o0; *(float4*)(dst+4) = o1;
}

// ---------- K1: normalize txt; bf16 K-chunked TXT[kc][cn(51008)][32]; invn[n*1000+c] ----------
__global__ void k_txt(const float* __restrict__ X, u16* __restrict__ TXT, float* __restrict__ invn){
  int cn = blockIdx.x, lane = threadIdx.x;
  int kc = lane>>2, kk8 = (lane&3)*8;
  size_t dstE = ((size_t)kc*51008 + cn)*32 + kk8;
  if (cn >= 51000){
    uint4 z = {0,0,0,0};
    *(uint4*)(TXT + dstE) = z;
    return;
  }
  int c = cn/51, n = cn - c*51;
  const float* src = X + ((size_t)n*1000 + c)*512 + lane*8;
  float4 a = *(const float4*)src;
  float4 d = *(const float4*)(src+4);
  float ss = a.x*a.x+a.y*a.y+a.z*a.z+a.w*a.w + d.x*d.x+d.y*d.y+d.z*d.z+d.w*d.w;
  ss = wsum(ss);
  float inv = 1.0f/sqrtf(ss);
  u16 h0=f2bf(a.x*inv),h1=f2bf(a.y*inv),h2=f2bf(a.z*inv),h3=f2bf(a.w*inv);
  u16 h4=f2bf(d.x*inv),h5=f2bf(d.y*inv),h6=f2bf(d.z*inv),h7=f2bf(d.w*inv);
  uint4 o;
  o.x = (unsigned)h0 | ((unsigned)h1<<16);
  o.y = (unsigned)h2 | ((unsigned)h3<<16);
  o.z = (unsigned)h4 | ((unsigned)h5<<16);
  o.w = (unsigned)h6 | ((unsigned)h7<<16);
  *(uint4*)(TXT + dstE) = o;
  if (lane==0) invn[(size_t)n*1000 + c] = inv;
}

// ---------- K2: mean_txt[c] = l2norm( sum_n txt_n[c] ) ----------
__global__ void k_mean(const float* __restrict__ X, const float* __restrict__ invn, float* __restrict__ MT){
  int c = blockIdx.x, tid = threadIdx.x, lane = tid&63, wv = tid>>6;
  __shared__ float sinv[51];
  __shared__ float red[4];
  if (tid < 51) sinv[tid] = invn[(size_t)tid*1000 + c];
  __syncthreads();
  int d0 = tid*2;
  float sx=0.f, sy=0.f;
  for (int n=0;n<51;++n){
    const float2 x = *(const float2*)(X + ((size_t)n*1000 + c)*512 + d0);
    float iv = sinv[n];
    sx += x.x*iv; sy += x.y*iv;
  }
  float ss = sx*sx + sy*sy;
  ss = wsum(ss);
  if (lane==0) red[wv] = ss;
  __syncthreads();
  float tot = red[0]+red[1]+red[2]+red[3];
  float inv = 1.0f/sqrtf(tot);
  float2 o = {sx*inv, sy*inv};
  *(float2*)(MT + (size_t)c*512 + d0) = o;
}

// ---------- K3: v[c,n] = softmax_n( TEMP * mean_txt[c].txt[n,c] ) ----------
__global__ void k_v(const u16* __restrict__ TXT, const float* __restrict__ MT, float* __restrict__ vbuf){
  int c = blockIdx.x, lane = threadIdx.x;
  __shared__ float lg[51];
  const float* mp = MT + (size_t)c*512 + lane*8;
  float4 m0 = *(const float4*)mp;
  float4 m1 = *(const float4*)(mp+4);
  int kc = lane>>2, kk8 = (lane&3)*8;
  for (int n=0;n<51;++n){
    size_t e = ((size_t)kc*51008 + (size_t)(c*51+n))*32 + kk8;
    uint4 q = *(const uint4*)(TXT + e);
    float d = bfl(q.x)*m0.x + bfh(q.x)*m0.y + bfl(q.y)*m0.z + bfh(q.y)*m0.w
            + bfl(q.z)*m1.x + bfh(q.z)*m1.y + bfl(q.w)*m1.z + bfh(q.w)*m1.w;
    d = wsum(d);
    if (lane==0) lg[n] = d;
  }
  __syncthreads();
  float val = (lane<51) ? lg[lane] : -1e30f;
  float mx = wmax(val);
  float e = (lane<51) ? expf(TEMP*(val-mx)) : 0.f;
  float s = wsum(e);
  if (lane<51) vbuf[(size_t)c*51 + lane] = e/s;
}

// ---------- K4: bias[b,c] = base_logits ----------
__global__ void k_base(const float* __restrict__ imgn, const float* __restrict__ MT, float* __restrict__ bias){
  int c = blockIdx.x, lane = threadIdx.x;
  const float* mp = MT + (size_t)c*512 + lane*8;
  float4 m0 = *(const float4*)mp;
  float4 m1 = *(const float4*)(mp+4);
  for (int b=0;b<32;++b){
    const float* ip = imgn + (size_t)b*512 + lane*8;
    float4 i0 = *(const float4*)ip;
    float4 i1 = *(const float4*)(ip+4);
    float d = i0.x*m0.x+i0.y*m0.y+i0.z*m0.z+i0.w*m0.w
            + i1.x*m1.x+i1.y*m1.y+i1.z*m1.z+i1.w*m1.w;
    d = wsum(d);
    if (lane==0) bias[(size_t)b*1000 + c] = d;
  }
}

// ---------- K5: normalize loc; LOC[b][kc][m(224)][32] bf16; ew[b,m] (0 for m>=196) ----------
__global__ void k_loc(const float* __restrict__ L, const float* __restrict__ imgn,
                      u16* __restrict__ LOC, float* __restrict__ ewg){
  int m = blockIdx.x, b = blockIdx.y, lane = threadIdx.x;
  size_t dstE = ((size_t)(b*16 + (lane>>2))*224 + m)*32 + (lane&3)*8;
  if (m >= 196){
    uint4 z = {0,0,0,0};
    *(uint4*)(LOC + dstE) = z;
    if (lane==0) ewg[(size_t)b*224 + m] = 0.f;
    return;
  }
  const float* src = L + ((size_t)b*196 + m)*512 + lane*8;
  float4 a = *(const float4*)src;
  float4 d = *(const float4*)(src+4);
  const float* ip = imgn + (size_t)b*512 + lane*8;
  float4 i0 = *(const float4*)ip;
  float4 i1 = *(const float4*)(ip+4);
  float ss = a.x*a.x+a.y*a.y+a.z*a.z+a.w*a.w + d.x*d.x+d.y*d.y+d.z*d.z+d.w*d.w;
  float ws = a.x*i0.x+a.y*i0.y+a.z*i0.z+a.w*i0.w + d.x*i1.x+d.y*i1.y+d.z*i1.z+d.w*i1.w;
  ss = wsum(ss); ws = wsum(ws);
  float inv = 1.0f/sqrtf(ss);
  u16 h0=f2bf(a.x*inv),h1=f2bf(a.y*inv),h2=f2bf(a.z*inv),h3=f2bf(a.w*inv);
  u16 h4=f2bf(d.x*inv),h5=f2bf(d.y*inv),h6=f2bf(d.z*inv),h7=f2bf(d.w*inv);
  uint4 o;
  o.x = (unsigned)h0 | ((unsigned)h1<<16);
  o.y = (unsigned)h2 | ((unsigned)h3<<16);
  o.z = (unsigned)h4 | ((unsigned)h5<<16);
  o.w = (unsigned)h6 | ((unsigned)h7<<16);
  *(uint4*)(LOC + dstE) = o;
  if (lane==0) ewg[(size_t)b*224 + m] = expf(TEMP * ws * inv);
}

struct B2 { bf16x8 x, y; };

// ---------- K6: fused GEMM (MFMA bf16) + in-register top-50 + weighted sum ----------
// THIS ROUND: kill the 4.86e7 LDS bank conflicts on the A-fragment ds_read_b128s.
// A rows are 64B (16 dwords = half the banks); per 16-lane phase (fixed quad,
// l16=0..15) the old layout hit only 2 bank-quartets (4*(r&1)+quad) -> 8 acc/bank
// (4x the minimum 2), ~4.3 extra cyc/read * 11.4M reads = the measured counter.
// Fix (rule both-sides-or-neither, global_load_lds writes linearly): bijective
// 16B-unit swizzle sigma(u) = u ^ ((u>>3)&3).
//   - stage: per-lane GLOBAL source unit = ch0 + (lane ^ ((lane>>3)&3))
//     (ch0 is a multiple of 64 -> bits 3,4 come from lane)
//   - read:  slot quad ^ ((l16>>1)&3) (row bits 1,2 == l16 bits 1,2; 112*ms and
//     16*t only touch bits >=4)
// Both are per-lane constants hoisted out of all loops. After swizzle each
// 16-lane phase covers all 8 quartets x2 = the free 2-way case.
// Epilogue unchanged (exchange stride 29 units: 5*l16 mod 8 already even).
// acc[] compile-time indices only (scratch-demotion trap).
__global__ __launch_bounds__(256,4) void k_main(const u16* __restrict__ TXT, const u16* __restrict__ LOC,
                                                const float* __restrict__ ewg, const float* __restrict__ vbuf,
                                                float* __restrict__ bias){
  __shared__ __align__(16) char smem[30592];   // A dbuf 28672 | exchange 4x7424=29696 | ewl 896
  const int tid = threadIdx.x, lane = tid & 63, wv = tid >> 6;
  const int quad = lane >> 4, l16 = lane & 15;
  const int ms = wv >> 1, ns = wv & 1;
  const int lsw = lane ^ ((lane>>3)&3);        // stage-side swizzled source lane
  const int qsw = (quad ^ ((l16>>1)&3)) * 16;  // read-side swizzled slot byte offset

  // group swizzle: groups of 32 cn-tiles x 32 b; last group 29 x 32
  int id = blockIdx.x, b, cnt_;
  if (id < 24576){
    int g = id >> 10, r = id & 1023;
    b = r >> 5;  cnt_ = (g << 5) + (r & 31);
  } else {
    int r = id - 24576;
    b = r / 29;  cnt_ = 768 + r % 29;
  }
  const int cn0 = cnt_ * 64;

  // stage ew early (region disjoint from A dbuf; read only after final K barrier)
  float* ewl = (float*)(smem + 29696);
  if (tid < 224) ewl[tid] = ewg[(size_t)b*224 + tid];

  const f32x4 zero = {0.f,0.f,0.f,0.f};
  f32x4 acc[7][2];
  #pragma unroll
  for (int t=0;t<7;++t){ acc[t][0]=zero; acc[t][1]=zero; }

  const u16* Abase = LOC + (size_t)(b*16)*224*32;
  char* Albd0 = smem;
  char* Albd1 = smem + 14336;

  auto stageA = [&](int kc, char* dst){
    const char* src = (const char*)(Abase + (size_t)kc*224*32);
    #pragma unroll
    for (int j=0;j<4;++j){
      int ch0 = j*256 + wv*64;                 // wave-uniform chunk base
      if (ch0 < 896)
        cp16(dst + (size_t)ch0*16, src + (size_t)(ch0 + lsw)*16);
    }
  };
  auto loadB = [&](int kc)->B2{
    B2 r;
    size_t e = ((size_t)kc*51008 + (size_t)(cn0 + 32*ns + l16))*32 + quad*8;
    r.x = *(const bf16x8*)(TXT + e);
    r.y = *(const bf16x8*)(TXT + e + 16*32);
    return r;
  };
  auto domfma = [&](const char* Ab, B2 bb){
    #pragma unroll
    for (int t=0;t<7;++t){
      bf16x8 af = *(const bf16x8*)(Ab + (size_t)((112*ms + 16*t + l16)*64) + qsw);
      acc[t][0] = __builtin_amdgcn_mfma_f32_16x16x32_bf16(af, bb.x, acc[t][0], 0,0,0);
      acc[t][1] = __builtin_amdgcn_mfma_f32_16x16x32_bf16(af, bb.y, acc[t][1], 0,0,0);
    }
  };

  stageA(0, Albd0);
  B2 bcur = loadB(0);
  __syncthreads();

  for (int kc = 0; kc < 16; ++kc){
    char* cur = (kc & 1) ? Albd1 : Albd0;
    char* nxt = (kc & 1) ? Albd0 : Albd1;
    B2 bnext;
    if (kc < 15){
      stageA(kc+1, nxt);
      bnext = loadB(kc+1);
    }
    domfma(cur, bcur);
    bcur = bnext;
    __syncthreads();
  }

  // ---- epilogue: exchange complementary m-half, then in-register selection ----
  // region(ns,j2) layout: [col l16][m-local 112+pad4] floats, stride 116 (2-way banks = free)
  {
    char* wr = smem + (size_t)(((ns<<1)|(ms^1))*7424) + l16*464;
    if (ms == 0){
      #pragma unroll
      for (int t=0;t<7;++t) *(f32x4*)(wr + (16*t+4*quad)*4) = acc[t][1];
    } else {
      #pragma unroll
      for (int t=0;t<7;++t) *(f32x4*)(wr + (16*t+4*quad)*4) = acc[t][0];
    }
  }
  __syncthreads();

  f32x4 own[7], oth[7];
  {
    const char* rd = smem + (size_t)(((ns<<1)|ms)*7424) + l16*464;
    #pragma unroll
    for (int t=0;t<7;++t) oth[t] = *(const f32x4*)(rd + (16*t+4*quad)*4);
    if (ms == 0){
      #pragma unroll
      for (int t=0;t<7;++t) own[t] = acc[t][0];
    } else {
      #pragma unroll
      for (int t=0;t<7;++t) own[t] = acc[t][1];
    }
  }
  // mask pad slots (m>=196) in whichever array holds m-half-1.
  // t=6 of the pad half is ALL pad -> it is skipped everywhere below, no mask needed.
  const float NEGF = -3.0e38f;
  {
    bool q0 = (quad == 0);
    if (ms == 1){
      #pragma unroll
      for (int r=0;r<4;++r){ own[5][r] = q0 ? own[5][r] : NEGF; }
    } else {
      #pragma unroll
      for (int r=0;r<4;++r){ oth[5][r] = q0 ? oth[5][r] : NEGF; }
    }
  }

  // bracket from t=0..4 (all real): cnt(lo)>=160>=50, cnt(hi)<=36<50
  float mn = own[0][0], mx = own[0][0];
  #pragma unroll
  for (int t=0;t<5;++t){
    #pragma unroll
    for (int r=0;r<4;++r){
      mn = fminf(mn, fminf(own[t][r], oth[t][r]));
      mx = fmaxf(mx, fmaxf(own[t][r], oth[t][r]));
    }
  }
  mn = qmin_f(mn);
  mx = qmax_f(mx);
  float lo = mn - 1e-6f, hi = mx + 1e-6f;
  float clo = 196.0f, chi = 0.0f;   // counts at lo/hi (clo is a safe over-estimate init)
  bool done = false;

  #pragma unroll 1
  for (int it = 0; it < 15; ++it){
    float w = hi - lo;
    float tm;
    if (it & 1){
      tm = lo + 0.5f*w;                               // guaranteed-halving floor
    } else {
      float fr = (clo - 50.0f) * __builtin_amdgcn_rcpf(clo - chi);
      fr = fminf(fmaxf(fr, 0.0625f), 0.9375f);        // clamped false position
      tm = lo + fr*w;
    }
    int c = 0;
    #pragma unroll
    for (int t=0;t<6;++t){
      #pragma unroll
      for (int r=0;r<4;++r){
        c += (own[t][r] >= tm) ? 1 : 0;
        c += (oth[t][r] >= tm) ? 1 : 0;
      }
    }
    if (ms == 1){            // real m-half-0 lives in oth; own[6] is all pad
      #pragma unroll
      for (int r=0;r<4;++r) c += (oth[6][r] >= tm) ? 1 : 0;
    } else {                 // real m-half-0 lives in own; oth[6] is all pad
      #pragma unroll
      for (int r=0;r<4;++r) c += (own[6][r] >= tm) ? 1 : 0;
    }
    c = qsum_i(c);
    bool ge = (c >= 50);
    bool upd = !done;
    if (upd &&  ge){ lo = tm; clo = (float)c; }
    if (upd && !ge){ hi = tm; chi = (float)c; }
    done = done || (c == 50) || ((hi - lo) < 5e-5f);
    if (__all(done)) break;
  }
  const float thr = lo;

  float num = 0.f, den = 0.f;
  #pragma unroll
  for (int t=0;t<6;++t){
    f32x4 eA = *(const f32x4*)(ewl + 112*ms     + 16*t + 4*quad);
    f32x4 eB = *(const f32x4*)(ewl + 112*(ms^1) + 16*t + 4*quad);
    #pragma unroll
    for (int r=0;r<4;++r){
      if (own[t][r] >= thr){ num = fmaf(own[t][r], eA[r], num); den += eA[r]; }
      if (oth[t][r] >= thr){ num = fmaf(oth[t][r], eB[r], num); den += eB[r]; }
    }
  }
  if (ms == 1){
    f32x4 eB = *(const f32x4*)(ewl + 112*(ms^1) + 96 + 4*quad);
    #pragma unroll
    for (int r=0;r<4;++r) if (oth[6][r] >= thr){ num = fmaf(oth[6][r], eB[r], num); den += eB[r]; }
  } else {
    f32x4 eA = *(const f32x4*)(ewl + 112*ms + 96 + 4*quad);
    #pragma unroll
    for (int r=0;r<4;++r) if (own[6][r] >= thr){ num = fmaf(own[6][r], eA[r], num); den += eA[r]; }
  }
  num = qsum_f(num);
  den = qsum_f(den);

  int cn = cn0 + 32*ns + 16*ms + l16;
  if (quad == 0 && cn < 51000){
    int c = cn/51;
    atomicAdd(bias + (size_t)b*1000 + c, vbuf[cn]*(num/den));
  }
}

// ---------- K7: out = fp32( exp(logit_scale) * bias ) ----------
__global__ void k_out(const float* __restrict__ bias, const float* __restrict__ ls, float* __restrict__ out){
  int i = blockIdx.x*256 + threadIdx.x;
  if (i < 32000){
    float sc = expf(ls[0]);
    out[i] = sc * bias[i];
  }
}

// ---------- launch ----------
extern "C" void kernel_launch(void* const* d_in, const int* in_sizes, int n_in,
                              void* d_out, int out_size, void* d_ws, size_t ws_size,
                              hipStream_t stream) {
  const float* img = (const float*)d_in[0];
  const float* loc = (const float*)d_in[1];
  const float* txt = (const float*)d_in[2];
  const float* ls  = (const float*)d_in[3];
  char* ws = (char*)d_ws;
  float* imgn = (float*)(ws + 0);            //  65536
  float* MT   = (float*)(ws + 65536);        //  2048000
  float* invn = (float*)(ws + 2113536);      //  204032
  float* vbuf = (float*)(ws + 2317568);      //  204032
  float* ewg  = (float*)(ws + 2521600);      //  28672
  float* bias = (float*)(ws + 2550272);      //  128000
  u16*   TXT  = (u16*)  (ws + 2678272);      //  52232192
  u16*   LOC  = (u16*)  (ws + 54910464);     //  7340032

  k_img <<<dim3(32),      dim3(64),  0, stream>>>(img, imgn);
  k_txt <<<dim3(51008),   dim3(64),  0, stream>>>(txt, TXT, invn);
  k_mean<<<dim3(1000),    dim3(256), 0, stream>>>(txt, invn, MT);
  k_v   <<<dim3(1000),    dim3(64),  0, stream>>>(TXT, MT, vbuf);
  k_base<<<dim3(1000),    dim3(64),  0, stream>>>(imgn, MT, bias);
  k_loc <<<dim3(224,32),  dim3(64),  0, stream>>>(loc, imgn, LOC, ewg);
  k_main<<<dim3(25504),   dim3(256), 0, stream>>>(TXT, LOC, ewg, vbuf, bias);
  k_out <<<dim3(125),     dim3(256), 0, stream>>>(bias, ls, (float*)d_out);
}

// Round 3
// 1027.394 us; speedup vs baseline: 1.1869x; 1.1869x over previous
//
#include <hip/hip_runtime.h>
#include <stdint.h>

typedef __bf16  bf16x8 __attribute__((ext_vector_type(8)));
typedef float   f32x4  __attribute__((ext_vector_type(4)));
typedef unsigned short u16;

#define TEMP 5.0f

// ---------- helpers ----------
__device__ inline float wsum(float v){
  #pragma unroll
  for (int off=32; off; off>>=1) v += __shfl_xor(v, off, 64);
  return v;
}
__device__ inline float wmax(float v){
  #pragma unroll
  for (int off=32; off; off>>=1) v = fmaxf(v, __shfl_xor(v, off, 64));
  return v;
}
__device__ inline u16 f2bf(float f){               // RNE float->bf16
  unsigned u = __float_as_uint(f);
  u = u + 0x7fffu + ((u>>16)&1u);
  return (u16)(u>>16);
}
__device__ inline float bfl(unsigned u){ return __uint_as_float(u<<16); }
__device__ inline float bfh(unsigned u){ return __uint_as_float(u & 0xffff0000u); }

// ---- cross-quad (lane ^16, ^32) reductions.
// gfx950 v_permlane16/32_swap: pure VALU, no LDS round-trip / lgkm wait.
#if __has_builtin(__builtin_amdgcn_permlane16_swap) && __has_builtin(__builtin_amdgcn_permlane32_swap)
__device__ inline int qsum_i(int c){
  auto a = __builtin_amdgcn_permlane16_swap((unsigned)c, (unsigned)c, false, false);
  c = (int)a[0] + (int)a[1];
  auto b = __builtin_amdgcn_permlane32_swap((unsigned)c, (unsigned)c, false, false);
  return (int)b[0] + (int)b[1];
}
__device__ inline float qsum_f(float v){
  auto a = __builtin_amdgcn_permlane16_swap(__float_as_uint(v), __float_as_uint(v), false, false);
  v = __uint_as_float(a[0]) + __uint_as_float(a[1]);
  auto b = __builtin_amdgcn_permlane32_swap(__float_as_uint(v), __float_as_uint(v), false, false);
  return __uint_as_float(b[0]) + __uint_as_float(b[1]);
}
__device__ inline float qmin_f(float v){
  auto a = __builtin_amdgcn_permlane16_swap(__float_as_uint(v), __float_as_uint(v), false, false);
  v = fminf(__uint_as_float(a[0]), __uint_as_float(a[1]));
  auto b = __builtin_amdgcn_permlane32_swap(__float_as_uint(v), __float_as_uint(v), false, false);
  return fminf(__uint_as_float(b[0]), __uint_as_float(b[1]));
}
__device__ inline float qmax_f(float v){
  auto a = __builtin_amdgcn_permlane16_swap(__float_as_uint(v), __float_as_uint(v), false, false);
  v = fmaxf(__uint_as_float(a[0]), __uint_as_float(a[1]));
  auto b = __builtin_amdgcn_permlane32_swap(__float_as_uint(v), __float_as_uint(v), false, false);
  return fmaxf(__uint_as_float(b[0]), __uint_as_float(b[1]));
}
#else
__device__ inline int qsum_i(int c){
  c += __shfl_xor(c, 16, 64); c += __shfl_xor(c, 32, 64); return c;
}
__device__ inline float qsum_f(float v){
  v += __shfl_xor(v, 16, 64); v += __shfl_xor(v, 32, 64); return v;
}
__device__ inline float qmin_f(float v){
  v = fminf(v, __shfl_xor(v, 16, 64)); v = fminf(v, __shfl_xor(v, 32, 64)); return v;
}
__device__ inline float qmax_f(float v){
  v = fmaxf(v, __shfl_xor(v, 16, 64)); v = fmaxf(v, __shfl_xor(v, 32, 64)); return v;
}
#endif

// async 16B global->LDS: lds dst is WAVE-UNIFORM base, HW adds lane*16
__device__ inline void cp16(void* lds_uniform, const void* g){
  __builtin_amdgcn_global_load_lds(
    (const __attribute__((address_space(1))) unsigned int*)g,
    (__attribute__((address_space(3))) unsigned int*)lds_uniform, 16, 0, 0);
}

// ---------- K0: normalize image features (32x512) ----------
__global__ void k_img(const float* __restrict__ X, float* __restrict__ imgn){
  int b = blockIdx.x, lane = threadIdx.x;
  const float* src = X + (size_t)b*512 + lane*8;
  float4 a = *(const float4*)src;
  float4 c = *(const float4*)(src+4);
  float ss = a.x*a.x+a.y*a.y+a.z*a.z+a.w*a.w + c.x*c.x+c.y*c.y+c.z*c.z+c.w*c.w;
  ss = wsum(ss);
  float inv = 1.0f/sqrtf(ss);
  float* dst = imgn + (size_t)b*512 + lane*8;
  float4 o0 = {a.x*inv,a.y*inv,a.z*inv,a.w*inv};
  float4 o1 = {c.x*inv,c.y*inv,c.z*inv,c.w*inv};
  *(float4*)dst = o0; *(float4*)(dst+4) = o1;
}

// ---------- K1: normalize txt; bf16 K-chunked TXT[kc][cn(51008)][32]; invn[n*1000+c] ----------
__global__ void k_txt(const float* __restrict__ X, u16* __restrict__ TXT, float* __restrict__ invn){
  int cn = blockIdx.x, lane = threadIdx.x;
  int kc = lane>>2, kk8 = (lane&3)*8;
  size_t dstE = ((size_t)kc*51008 + cn)*32 + kk8;
  if (cn >= 51000){
    uint4 z = {0,0,0,0};
    *(uint4*)(TXT + dstE) = z;
    return;
  }
  int c = cn/51, n = cn - c*51;
  const float* src = X + ((size_t)n*1000 + c)*512 + lane*8;
  float4 a = *(const float4*)src;
  float4 d = *(const float4*)(src+4);
  float ss = a.x*a.x+a.y*a.y+a.z*a.z+a.w*a.w + d.x*d.x+d.y*d.y+d.z*d.z+d.w*d.w;
  ss = wsum(ss);
  float inv = 1.0f/sqrtf(ss);
  u16 h0=f2bf(a.x*inv),h1=f2bf(a.y*inv),h2=f2bf(a.z*inv),h3=f2bf(a.w*inv);
  u16 h4=f2bf(d.x*inv),h5=f2bf(d.y*inv),h6=f2bf(d.z*inv),h7=f2bf(d.w*inv);
  uint4 o;
  o.x = (unsigned)h0 | ((unsigned)h1<<16);
  o.y = (unsigned)h2 | ((unsigned)h3<<16);
  o.z = (unsigned)h4 | ((unsigned)h5<<16);
  o.w = (unsigned)h6 | ((unsigned)h7<<16);
  *(uint4*)(TXT + dstE) = o;
  if (lane==0) invn[(size_t)n*1000 + c] = inv;
}

// ---------- K2: mean_txt[c] = l2norm( sum_n txt_n[c] ) ----------
__global__ void k_mean(const float* __restrict__ X, const float* __restrict__ invn, float* __restrict__ MT){
  int c = blockIdx.x, tid = threadIdx.x, lane = tid&63, wv = tid>>6;
  __shared__ float sinv[51];
  __shared__ float red[4];
  if (tid < 51) sinv[tid] = invn[(size_t)tid*1000 + c];
  __syncthreads();
  int d0 = tid*2;
  float sx=0.f, sy=0.f;
  for (int n=0;n<51;++n){
    const float2 x = *(const float2*)(X + ((size_t)n*1000 + c)*512 + d0);
    float iv = sinv[n];
    sx += x.x*iv; sy += x.y*iv;
  }
  float ss = sx*sx + sy*sy;
  ss = wsum(ss);
  if (lane==0) red[wv] = ss;
  __syncthreads();
  float tot = red[0]+red[1]+red[2]+red[3];
  float inv = 1.0f/sqrtf(tot);
  float2 o = {sx*inv, sy*inv};
  *(float2*)(MT + (size_t)c*512 + d0) = o;
}

// ---------- K3: v[c,n] = softmax_n( TEMP * mean_txt[c].txt[n,c] ) ----------
__global__ void k_v(const u16* __restrict__ TXT, const float* __restrict__ MT, float* __restrict__ vbuf){
  int c = blockIdx.x, lane = threadIdx.x;
  __shared__ float lg[51];
  const float* mp = MT + (size_t)c*512 + lane*8;
  float4 m0 = *(const float4*)mp;
  float4 m1 = *(const float4*)(mp+4);
  int kc = lane>>2, kk8 = (lane&3)*8;
  for (int n=0;n<51;++n){
    size_t e = ((size_t)kc*51008 + (size_t)(c*51+n))*32 + kk8;
    uint4 q = *(const uint4*)(TXT + e);
    float d = bfl(q.x)*m0.x + bfh(q.x)*m0.y + bfl(q.y)*m0.z + bfh(q.y)*m0.w
            + bfl(q.z)*m1.x + bfh(q.z)*m1.y + bfl(q.w)*m1.z + bfh(q.w)*m1.w;
    d = wsum(d);
    if (lane==0) lg[n] = d;
  }
  __syncthreads();
  float val = (lane<51) ? lg[lane] : -1e30f;
  float mx = wmax(val);
  float e = (lane<51) ? expf(TEMP*(val-mx)) : 0.f;
  float s = wsum(e);
  if (lane<51) vbuf[(size_t)c*51 + lane] = e/s;
}

// ---------- K4: bias[b,c] = base_logits ----------
__global__ void k_base(const float* __restrict__ imgn, const float* __restrict__ MT, float* __restrict__ bias){
  int c = blockIdx.x, lane = threadIdx.x;
  const float* mp = MT + (size_t)c*512 + lane*8;
  float4 m0 = *(const float4*)mp;
  float4 m1 = *(const float4*)(mp+4);
  for (int b=0;b<32;++b){
    const float* ip = imgn + (size_t)b*512 + lane*8;
    float4 i0 = *(const float4*)ip;
    float4 i1 = *(const float4*)(ip+4);
    float d = i0.x*m0.x+i0.y*m0.y+i0.z*m0.z+i0.w*m0.w
            + i1.x*m1.x+i1.y*m1.y+i1.z*m1.z+i1.w*m1.w;
    d = wsum(d);
    if (lane==0) bias[(size_t)b*1000 + c] = d;
  }
}

// ---------- K5: normalize loc; LOC[b][kc][m(224)][32] bf16; ew[b,m] (0 for m>=196) ----------
__global__ void k_loc(const float* __restrict__ L, const float* __restrict__ imgn,
                      u16* __restrict__ LOC, float* __restrict__ ewg){
  int m = blockIdx.x, b = blockIdx.y, lane = threadIdx.x;
  size_t dstE = ((size_t)(b*16 + (lane>>2))*224 + m)*32 + (lane&3)*8;
  if (m >= 196){
    uint4 z = {0,0,0,0};
    *(uint4*)(LOC + dstE) = z;
    if (lane==0) ewg[(size_t)b*224 + m] = 0.f;
    return;
  }
  const float* src = L + ((size_t)b*196 + m)*512 + lane*8;
  float4 a = *(const float4*)src;
  float4 d = *(const float4*)(src+4);
  const float* ip = imgn + (size_t)b*512 + lane*8;
  float4 i0 = *(const float4*)ip;
  float4 i1 = *(const float4*)(ip+4);
  float ss = a.x*a.x+a.y*a.y+a.z*a.z+a.w*a.w + d.x*d.x+d.y*d.y+d.z*d.z+d.w*d.w;
  float ws = a.x*i0.x+a.y*i0.y+a.z*i0.z+a.w*i0.w + d.x*i1.x+d.y*i1.y+d.z*i1.z+d.w*i1.w;
  ss = wsum(ss); ws = wsum(ws);
  float inv = 1.0f/sqrtf(ss);
  u16 h0=f2bf(a.x*inv),h1=f2bf(a.y*inv),h2=f2bf(a.z*inv),h3=f2bf(a.w*inv);
  u16 h4=f2bf(d.x*inv),h5=f2bf(d.y*inv),h6=f2bf(d.z*inv),h7=f2bf(d.w*inv);
  uint4 o;
  o.x = (unsigned)h0 | ((unsigned)h1<<16);
  o.y = (unsigned)h2 | ((unsigned)h3<<16);
  o.z = (unsigned)h4 | ((unsigned)h5<<16);
  o.w = (unsigned)h6 | ((unsigned)h7<<16);
  *(uint4*)(LOC + dstE) = o;
  if (lane==0) ewg[(size_t)b*224 + m] = expf(TEMP * ws * inv);
}

struct B2 { bf16x8 x, y; };

// ---------- K6: fused GEMM (MFMA bf16) + in-register top-50 + weighted sum ----------
// THIS ROUND: occupancy. R2 post-mortem: bank conflicts fixed (4.86e7->2.86e6)
// with ZERO time delta -> LDS wasn't the critical path. Model: MfmaUtil 15.5 +
// VALU-only ~33 = ~49% issue occupancy, no pipe saturated -> stall-bound
// (vmcnt(0) drain at every per-kc __syncthreads + barrier skew). Occupancy was
// capped at 45% by __launch_bounds__(256,4) = 4 blocks/CU, NOT by resources:
// LDS 30720B x 5 = 153.6KB <= 160KB, VGPR 60 << 409. -> (256,5): 5th
// independent block per CU fills barrier-drain holes with TLP.
// (History: A-fragment swizzle sigma(u)=u^((u>>3)&3) both-sides, permlane
// epilogue reduces, interpolated bisection with exact-50 early exit.)
// acc[] compile-time indices only (scratch-demotion trap).
__global__ __launch_bounds__(256,5) void k_main(const u16* __restrict__ TXT, const u16* __restrict__ LOC,
                                                const float* __restrict__ ewg, const float* __restrict__ vbuf,
                                                float* __restrict__ bias){
  __shared__ __align__(16) char smem[30592];   // A dbuf 28672 | exchange 4x7424=29696 | ewl 896
  const int tid = threadIdx.x, lane = tid & 63, wv = tid >> 6;
  const int quad = lane >> 4, l16 = lane & 15;
  const int ms = wv >> 1, ns = wv & 1;
  const int lsw = lane ^ ((lane>>3)&3);        // stage-side swizzled source lane
  const int qsw = (quad ^ ((l16>>1)&3)) * 16;  // read-side swizzled slot byte offset

  // group swizzle: groups of 32 cn-tiles x 32 b; last group 29 x 32
  int id = blockIdx.x, b, cnt_;
  if (id < 24576){
    int g = id >> 10, r = id & 1023;
    b = r >> 5;  cnt_ = (g << 5) + (r & 31);
  } else {
    int r = id - 24576;
    b = r / 29;  cnt_ = 768 + r % 29;
  }
  const int cn0 = cnt_ * 64;

  // stage ew early (region disjoint from A dbuf; read only after final K barrier)
  float* ewl = (float*)(smem + 29696);
  if (tid < 224) ewl[tid] = ewg[(size_t)b*224 + tid];

  const f32x4 zero = {0.f,0.f,0.f,0.f};
  f32x4 acc[7][2];
  #pragma unroll
  for (int t=0;t<7;++t){ acc[t][0]=zero; acc[t][1]=zero; }

  const u16* Abase = LOC + (size_t)(b*16)*224*32;
  char* Albd0 = smem;
  char* Albd1 = smem + 14336;

  auto stageA = [&](int kc, char* dst){
    const char* src = (const char*)(Abase + (size_t)kc*224*32);
    #pragma unroll
    for (int j=0;j<4;++j){
      int ch0 = j*256 + wv*64;                 // wave-uniform chunk base
      if (ch0 < 896)
        cp16(dst + (size_t)ch0*16, src + (size_t)(ch0 + lsw)*16);
    }
  };
  auto loadB = [&](int kc)->B2{
    B2 r;
    size_t e = ((size_t)kc*51008 + (size_t)(cn0 + 32*ns + l16))*32 + quad*8;
    r.x = *(const bf16x8*)(TXT + e);
    r.y = *(const bf16x8*)(TXT + e + 16*32);
    return r;
  };
  auto domfma = [&](const char* Ab, B2 bb){
    #pragma unroll
    for (int t=0;t<7;++t){
      bf16x8 af = *(const bf16x8*)(Ab + (size_t)((112*ms + 16*t + l16)*64) + qsw);
      acc[t][0] = __builtin_amdgcn_mfma_f32_16x16x32_bf16(af, bb.x, acc[t][0], 0,0,0);
      acc[t][1] = __builtin_amdgcn_mfma_f32_16x16x32_bf16(af, bb.y, acc[t][1], 0,0,0);
    }
  };

  stageA(0, Albd0);
  B2 bcur = loadB(0);
  __syncthreads();

  for (int kc = 0; kc < 16; ++kc){
    char* cur = (kc & 1) ? Albd1 : Albd0;
    char* nxt = (kc & 1) ? Albd0 : Albd1;
    B2 bnext;
    if (kc < 15){
      stageA(kc+1, nxt);
      bnext = loadB(kc+1);
    }
    domfma(cur, bcur);
    bcur = bnext;
    __syncthreads();
  }

  // ---- epilogue: exchange complementary m-half, then in-register selection ----
  // region(ns,j2) layout: [col l16][m-local 112+pad4] floats, stride 116 (2-way banks = free)
  {
    char* wr = smem + (size_t)(((ns<<1)|(ms^1))*7424) + l16*464;
    if (ms == 0){
      #pragma unroll
      for (int t=0;t<7;++t) *(f32x4*)(wr + (16*t+4*quad)*4) = acc[t][1];
    } else {
      #pragma unroll
      for (int t=0;t<7;++t) *(f32x4*)(wr + (16*t+4*quad)*4) = acc[t][0];
    }
  }
  __syncthreads();

  f32x4 own[7], oth[7];
  {
    const char* rd = smem + (size_t)(((ns<<1)|ms)*7424) + l16*464;
    #pragma unroll
    for (int t=0;t<7;++t) oth[t] = *(const f32x4*)(rd + (16*t+4*quad)*4);
    if (ms == 0){
      #pragma unroll
      for (int t=0;t<7;++t) own[t] = acc[t][0];
    } else {
      #pragma unroll
      for (int t=0;t<7;++t) own[t] = acc[t][1];
    }
  }
  // mask pad slots (m>=196) in whichever array holds m-half-1.
  // t=6 of the pad half is ALL pad -> it is skipped everywhere below, no mask needed.
  const float NEGF = -3.0e38f;
  {
    bool q0 = (quad == 0);
    if (ms == 1){
      #pragma unroll
      for (int r=0;r<4;++r){ own[5][r] = q0 ? own[5][r] : NEGF; }
    } else {
      #pragma unroll
      for (int r=0;r<4;++r){ oth[5][r] = q0 ? oth[5][r] : NEGF; }
    }
  }

  // bracket from t=0..4 (all real): cnt(lo)>=160>=50, cnt(hi)<=36<50
  float mn = own[0][0], mx = own[0][0];
  #pragma unroll
  for (int t=0;t<5;++t){
    #pragma unroll
    for (int r=0;r<4;++r){
      mn = fminf(mn, fminf(own[t][r], oth[t][r]));
      mx = fmaxf(mx, fmaxf(own[t][r], oth[t][r]));
    }
  }
  mn = qmin_f(mn);
  mx = qmax_f(mx);
  float lo = mn - 1e-6f, hi = mx + 1e-6f;
  float clo = 196.0f, chi = 0.0f;   // counts at lo/hi (clo is a safe over-estimate init)
  bool done = false;

  #pragma unroll 1
  for (int it = 0; it < 15; ++it){
    float w = hi - lo;
    float tm;
    if (it & 1){
      tm = lo + 0.5f*w;                               // guaranteed-halving floor
    } else {
      float fr = (clo - 50.0f) * __builtin_amdgcn_rcpf(clo - chi);
      fr = fminf(fmaxf(fr, 0.0625f), 0.9375f);        // clamped false position
      tm = lo + fr*w;
    }
    int c = 0;
    #pragma unroll
    for (int t=0;t<6;++t){
      #pragma unroll
      for (int r=0;r<4;++r){
        c += (own[t][r] >= tm) ? 1 : 0;
        c += (oth[t][r] >= tm) ? 1 : 0;
      }
    }
    if (ms == 1){            // real m-half-0 lives in oth; own[6] is all pad
      #pragma unroll
      for (int r=0;r<4;++r) c += (oth[6][r] >= tm) ? 1 : 0;
    } else {                 // real m-half-0 lives in own; oth[6] is all pad
      #pragma unroll
      for (int r=0;r<4;++r) c += (own[6][r] >= tm) ? 1 : 0;
    }
    c = qsum_i(c);
    bool ge = (c >= 50);
    bool upd = !done;
    if (upd &&  ge){ lo = tm; clo = (float)c; }
    if (upd && !ge){ hi = tm; chi = (float)c; }
    done = done || (c == 50) || ((hi - lo) < 5e-5f);
    if (__all(done)) break;
  }
  const float thr = lo;

  float num = 0.f, den = 0.f;
  #pragma unroll
  for (int t=0;t<6;++t){
    f32x4 eA = *(const f32x4*)(ewl + 112*ms     + 16*t + 4*quad);
    f32x4 eB = *(const f32x4*)(ewl + 112*(ms^1) + 16*t + 4*quad);
    #pragma unroll
    for (int r=0;r<4;++r){
      if (own[t][r] >= thr){ num = fmaf(own[t][r], eA[r], num); den += eA[r]; }
      if (oth[t][r] >= thr){ num = fmaf(oth[t][r], eB[r], num); den += eB[r]; }
    }
  }
  if (ms == 1){
    f32x4 eB = *(const f32x4*)(ewl + 112*(ms^1) + 96 + 4*quad);
    #pragma unroll
    for (int r=0;r<4;++r) if (oth[6][r] >= thr){ num = fmaf(oth[6][r], eB[r], num); den += eB[r]; }
  } else {
    f32x4 eA = *(const f32x4*)(ewl + 112*ms + 96 + 4*quad);
    #pragma unroll
    for (int r=0;r<4;++r) if (own[6][r] >= thr){ num = fmaf(own[6][r], eA[r], num); den += eA[r]; }
  }
  num = qsum_f(num);
  den = qsum_f(den);

  int cn = cn0 + 32*ns + 16*ms + l16;
  if (quad == 0 && cn < 51000){
    int c = cn/51;
    atomicAdd(bias + (size_t)b*1000 + c, vbuf[cn]*(num/den));
  }
}

// ---------- K7: out = fp32( exp(logit_scale) * bias ) ----------
__global__ void k_out(const float* __restrict__ bias, const float* __restrict__ ls, float* __restrict__ out){
  int i = blockIdx.x*256 + threadIdx.x;
  if (i < 32000){
    float sc = expf(ls[0]);
    out[i] = sc * bias[i];
  }
}

// ---------- launch ----------
extern "C" void kernel_launch(void* const* d_in, const int* in_sizes, int n_in,
                              void* d_out, int out_size, void* d_ws, size_t ws_size,
                              hipStream_t stream) {
  const float* img = (const float*)d_in[0];
  const float* loc = (const float*)d_in[1];
  const float* txt = (const float*)d_in[2];
  const float* ls  = (const float*)d_in[3];
  char* ws = (char*)d_ws;
  float* imgn = (float*)(ws + 0);            //  65536
  float* MT   = (float*)(ws + 65536);        //  2048000
  float* invn = (float*)(ws + 2113536);      //  204032
  float* vbuf = (float*)(ws + 2317568);      //  204032
  float* ewg  = (float*)(ws + 2521600);      //  28672
  float* bias = (float*)(ws + 2550272);      //  128000
  u16*   TXT  = (u16*)  (ws + 2678272);      //  52232192
  u16*   LOC  = (u16*)  (ws + 54910464);     //  7340032

  k_img <<<dim3(32),      dim3(64),  0, stream>>>(img, imgn);
  k_txt <<<dim3(51008),   dim3(64),  0, stream>>>(txt, TXT, invn);
  k_mean<<<dim3(1000),    dim3(256), 0, stream>>>(txt, invn, MT);
  k_v   <<<dim3(1000),    dim3(64),  0, stream>>>(TXT, MT, vbuf);
  k_base<<<dim3(1000),    dim3(64),  0, stream>>>(imgn, MT, bias);
  k_loc <<<dim3(224,32),  dim3(64),  0, stream>>>(loc, imgn, LOC, ewg);
  k_main<<<dim3(25504),   dim3(256), 0, stream>>>(TXT, LOC, ewg, vbuf, bias);
  k_out <<<dim3(125),     dim3(256), 0, stream>>>(bias, ls, (float*)d_out);
}

// Round 4
// 985.379 us; speedup vs baseline: 1.2375x; 1.0426x over previous
//
#include <hip/hip_runtime.h>
#include <stdint.h>

typedef __bf16  bf16x8 __attribute__((ext_vector_type(8)));
typedef float   f32x4  __attribute__((ext_vector_type(4)));
typedef short   s16x2  __attribute__((ext_vector_type(2)));
typedef unsigned short u16;

#define TEMP 5.0f

// ---------- helpers ----------
__device__ inline float wsum(float v){
  #pragma unroll
  for (int off=32; off; off>>=1) v += __shfl_xor(v, off, 64);
  return v;
}
__device__ inline float wmax(float v){
  #pragma unroll
  for (int off=32; off; off>>=1) v = fmaxf(v, __shfl_xor(v, off, 64));
  return v;
}
__device__ inline u16 f2bf(float f){               // RNE float->bf16
  unsigned u = __float_as_uint(f);
  u = u + 0x7fffu + ((u>>16)&1u);
  return (u16)(u>>16);
}
__device__ inline float bfl(unsigned u){ return __uint_as_float(u<<16); }
__device__ inline float bfh(unsigned u){ return __uint_as_float(u & 0xffff0000u); }

__device__ inline s16x2 as_s16x2(int v){ union{int i; s16x2 v;} u; u.i=v; return u.v; }

// ---- cross-quad (lane ^16, ^32) reductions: pure VALU permlane swaps.
#if __has_builtin(__builtin_amdgcn_permlane16_swap) && __has_builtin(__builtin_amdgcn_permlane32_swap)
__device__ inline int qsum_i(int c){
  auto a = __builtin_amdgcn_permlane16_swap((unsigned)c, (unsigned)c, false, false);
  c = (int)a[0] + (int)a[1];
  auto b = __builtin_amdgcn_permlane32_swap((unsigned)c, (unsigned)c, false, false);
  return (int)b[0] + (int)b[1];
}
__device__ inline float qsum_f(float v){
  auto a = __builtin_amdgcn_permlane16_swap(__float_as_uint(v), __float_as_uint(v), false, false);
  v = __uint_as_float(a[0]) + __uint_as_float(a[1]);
  auto b = __builtin_amdgcn_permlane32_swap(__float_as_uint(v), __float_as_uint(v), false, false);
  return __uint_as_float(b[0]) + __uint_as_float(b[1]);
}
__device__ inline int qmin_i(int v){
  auto a = __builtin_amdgcn_permlane16_swap((unsigned)v, (unsigned)v, false, false);
  v = min((int)a[0], (int)a[1]);
  auto b = __builtin_amdgcn_permlane32_swap((unsigned)v, (unsigned)v, false, false);
  return min((int)b[0], (int)b[1]);
}
__device__ inline int qmax_i(int v){
  auto a = __builtin_amdgcn_permlane16_swap((unsigned)v, (unsigned)v, false, false);
  v = max((int)a[0], (int)a[1]);
  auto b = __builtin_amdgcn_permlane32_swap((unsigned)v, (unsigned)v, false, false);
  return max((int)b[0], (int)b[1]);
}
#else
__device__ inline int qsum_i(int c){
  c += __shfl_xor(c, 16, 64); c += __shfl_xor(c, 32, 64); return c;
}
__device__ inline float qsum_f(float v){
  v += __shfl_xor(v, 16, 64); v += __shfl_xor(v, 32, 64); return v;
}
__device__ inline int qmin_i(int v){
  v = min(v, __shfl_xor(v, 16, 64)); v = min(v, __shfl_xor(v, 32, 64)); return v;
}
__device__ inline int qmax_i(int v){
  v = max(v, __shfl_xor(v, 16, 64)); v = max(v, __shfl_xor(v, 32, 64)); return v;
}
#endif

__device__ inline s16x2 pkmin2(s16x2 a, s16x2 b){
  s16x2 r; r.x = a.x < b.x ? a.x : b.x; r.y = a.y < b.y ? a.y : b.y; return r;
}
__device__ inline s16x2 pkmax2(s16x2 a, s16x2 b){
  s16x2 r; r.x = a.x > b.x ? a.x : b.x; r.y = a.y > b.y ? a.y : b.y; return r;
}

// async 16B global->LDS: lds dst is WAVE-UNIFORM base, HW adds lane*16
__device__ inline void cp16(void* lds_uniform, const void* g){
  __builtin_amdgcn_global_load_lds(
    (const __attribute__((address_space(1))) unsigned int*)g,
    (__attribute__((address_space(3))) unsigned int*)lds_uniform, 16, 0, 0);
}

// ---------- K0: normalize image features (32x512) ----------
__global__ void k_img(const float* __restrict__ X, float* __restrict__ imgn){
  int b = blockIdx.x, lane = threadIdx.x;
  const float* src = X + (size_t)b*512 + lane*8;
  float4 a = *(const float4*)src;
  float4 c = *(const float4*)(src+4);
  float ss = a.x*a.x+a.y*a.y+a.z*a.z+a.w*a.w + c.x*c.x+c.y*c.y+c.z*c.z+c.w*c.w;
  ss = wsum(ss);
  float inv = 1.0f/sqrtf(ss);
  float* dst = imgn + (size_t)b*512 + lane*8;
  float4 o0 = {a.x*inv,a.y*inv,a.z*inv,a.w*inv};
  float4 o1 = {c.x*inv,c.y*inv,c.z*inv,c.w*inv};
  *(float4*)dst = o0; *(float4*)(dst+4) = o1;
}

// ---------- K1: normalize txt; bf16 K-chunked TXT[kc][cn(51008)][32]; invn[n*1000+c] ----------
__global__ void k_txt(const float* __restrict__ X, u16* __restrict__ TXT, float* __restrict__ invn){
  int cn = blockIdx.x, lane = threadIdx.x;
  int kc = lane>>2, kk8 = (lane&3)*8;
  size_t dstE = ((size_t)kc*51008 + cn)*32 + kk8;
  if (cn >= 51000){
    uint4 z = {0,0,0,0};
    *(uint4*)(TXT + dstE) = z;
    return;
  }
  int c = cn/51, n = cn - c*51;
  const float* src = X + ((size_t)n*1000 + c)*512 + lane*8;
  float4 a = *(const float4*)src;
  float4 d = *(const float4*)(src+4);
  float ss = a.x*a.x+a.y*a.y+a.z*a.z+a.w*a.w + d.x*d.x+d.y*d.y+d.z*d.z+d.w*d.w;
  ss = wsum(ss);
  float inv = 1.0f/sqrtf(ss);
  u16 h0=f2bf(a.x*inv),h1=f2bf(a.y*inv),h2=f2bf(a.z*inv),h3=f2bf(a.w*inv);
  u16 h4=f2bf(d.x*inv),h5=f2bf(d.y*inv),h6=f2bf(d.z*inv),h7=f2bf(d.w*inv);
  uint4 o;
  o.x = (unsigned)h0 | ((unsigned)h1<<16);
  o.y = (unsigned)h2 | ((unsigned)h3<<16);
  o.z = (unsigned)h4 | ((unsigned)h5<<16);
  o.w = (unsigned)h6 | ((unsigned)h7<<16);
  *(uint4*)(TXT + dstE) = o;
  if (lane==0) invn[(size_t)n*1000 + c] = inv;
}

// ---------- K2: mean_txt[c] = l2norm( sum_n txt_n[c] ) ----------
__global__ void k_mean(const float* __restrict__ X, const float* __restrict__ invn, float* __restrict__ MT){
  int c = blockIdx.x, tid = threadIdx.x, lane = tid&63, wv = tid>>6;
  __shared__ float sinv[51];
  __shared__ float red[4];
  if (tid < 51) sinv[tid] = invn[(size_t)tid*1000 + c];
  __syncthreads();
  int d0 = tid*2;
  float sx=0.f, sy=0.f;
  for (int n=0;n<51;++n){
    const float2 x = *(const float2*)(X + ((size_t)n*1000 + c)*512 + d0);
    float iv = sinv[n];
    sx += x.x*iv; sy += x.y*iv;
  }
  float ss = sx*sx + sy*sy;
  ss = wsum(ss);
  if (lane==0) red[wv] = ss;
  __syncthreads();
  float tot = red[0]+red[1]+red[2]+red[3];
  float inv = 1.0f/sqrtf(tot);
  float2 o = {sx*inv, sy*inv};
  *(float2*)(MT + (size_t)c*512 + d0) = o;
}

// ---------- K3: v[c,n] = softmax_n( TEMP * mean_txt[c].txt[n,c] ) ----------
__global__ void k_v(const u16* __restrict__ TXT, const float* __restrict__ MT, float* __restrict__ vbuf){
  int c = blockIdx.x, lane = threadIdx.x;
  __shared__ float lg[51];
  const float* mp = MT + (size_t)c*512 + lane*8;
  float4 m0 = *(const float4*)mp;
  float4 m1 = *(const float4*)(mp+4);
  int kc = lane>>2, kk8 = (lane&3)*8;
  for (int n=0;n<51;++n){
    size_t e = ((size_t)kc*51008 + (size_t)(c*51+n))*32 + kk8;
    uint4 q = *(const uint4*)(TXT + e);
    float d = bfl(q.x)*m0.x + bfh(q.x)*m0.y + bfl(q.y)*m0.z + bfh(q.y)*m0.w
            + bfl(q.z)*m1.x + bfh(q.z)*m1.y + bfl(q.w)*m1.z + bfh(q.w)*m1.w;
    d = wsum(d);
    if (lane==0) lg[n] = d;
  }
  __syncthreads();
  float val = (lane<51) ? lg[lane] : -1e30f;
  float mx = wmax(val);
  float e = (lane<51) ? expf(TEMP*(val-mx)) : 0.f;
  float s = wsum(e);
  if (lane<51) vbuf[(size_t)c*51 + lane] = e/s;
}

// ---------- K4: bias[b,c] = base_logits ----------
__global__ void k_base(const float* __restrict__ imgn, const float* __restrict__ MT, float* __restrict__ bias){
  int c = blockIdx.x, lane = threadIdx.x;
  const float* mp = MT + (size_t)c*512 + lane*8;
  float4 m0 = *(const float4*)mp;
  float4 m1 = *(const float4*)(mp+4);
  for (int b=0;b<32;++b){
    const float* ip = imgn + (size_t)b*512 + lane*8;
    float4 i0 = *(const float4*)ip;
    float4 i1 = *(const float4*)(ip+4);
    float d = i0.x*m0.x+i0.y*m0.y+i0.z*m0.z+i0.w*m0.w
            + i1.x*m1.x+i1.y*m1.y+i1.z*m1.z+i1.w*m1.w;
    d = wsum(d);
    if (lane==0) bias[(size_t)b*1000 + c] = d;
  }
}

// ---------- K5: normalize loc; LOC[b][kc][m(224)][32] bf16; ew[b,m] (0 for m>=196) ----------
__global__ void k_loc(const float* __restrict__ L, const float* __restrict__ imgn,
                      u16* __restrict__ LOC, float* __restrict__ ewg){
  int m = blockIdx.x, b = blockIdx.y, lane = threadIdx.x;
  size_t dstE = ((size_t)(b*16 + (lane>>2))*224 + m)*32 + (lane&3)*8;
  if (m >= 196){
    uint4 z = {0,0,0,0};
    *(uint4*)(LOC + dstE) = z;
    if (lane==0) ewg[(size_t)b*224 + m] = 0.f;
    return;
  }
  const float* src = L + ((size_t)b*196 + m)*512 + lane*8;
  float4 a = *(const float4*)src;
  float4 d = *(const float4*)(src+4);
  const float* ip = imgn + (size_t)b*512 + lane*8;
  float4 i0 = *(const float4*)ip;
  float4 i1 = *(const float4*)(ip+4);
  float ss = a.x*a.x+a.y*a.y+a.z*a.z+a.w*a.w + d.x*d.x+d.y*d.y+d.z*d.z+d.w*d.w;
  float ws = a.x*i0.x+a.y*i0.y+a.z*i0.z+a.w*i0.w + d.x*i1.x+d.y*i1.y+d.z*i1.z+d.w*i1.w;
  ss = wsum(ss); ws = wsum(ws);
  float inv = 1.0f/sqrtf(ss);
  u16 h0=f2bf(a.x*inv),h1=f2bf(a.y*inv),h2=f2bf(a.z*inv),h3=f2bf(a.w*inv);
  u16 h4=f2bf(d.x*inv),h5=f2bf(d.y*inv),h6=f2bf(d.z*inv),h7=f2bf(d.w*inv);
  uint4 o;
  o.x = (unsigned)h0 | ((unsigned)h1<<16);
  o.y = (unsigned)h2 | ((unsigned)h3<<16);
  o.z = (unsigned)h4 | ((unsigned)h5<<16);
  o.w = (unsigned)h6 | ((unsigned)h7<<16);
  *(uint4*)(LOC + dstE) = o;
  if (lane==0) ewg[(size_t)b*224 + m] = expf(TEMP * ws * inv);
}

struct B2 { bf16x8 x, y; };

// ---------- K6: fused GEMM (MFMA bf16) + in-register top-50 + weighted sum ----------
// THIS ROUND: integer-key packed selection. R3 post-mortem: occupancy fix worked
// (850us, VALU 63.7 = top pipe; VALU-proper ~44% after subtracting MFMA share,
// ~75% of it in the epilogue). New epilogue:
//  * order-preserving 16-bit keys k=(int)(x*15360) (granularity 6.5e-5 << bf16
//    membership noise ~1e-3), packed pairs in 32-bit regs.
//  * count probe = v_pk_sub_i16 / v_pk_ashrrev_i16 / v_pk_add_i16 -> 1.5
//    VALU/elem (was 2), pads self-exclude via sentinel key 0xC180 (-16000),
//    no float NEGF masking, uniform 28-pair loop (no asymmetric t=6 branches).
//  * bracket via packed pk_min/pk_max over t=0..4 (160 samples: cnt(lo)>=160,
//    cnt(hi)<=36 -> valid bounds). |key - tm| <= 31668 < 32768: no i16 overflow.
//  * integer false position + Illinois stagnation control; exits: exact c==50
//    (perfect threshold) or hi-lo<=1 (key-resolution); cap 14. thr = lo.
// (History: A-swizzle sigma(u)=u^((u>>3)&3) both-sides; permlane reduces;
// launch_bounds (256,5) = 5 blocks/CU.)
// acc[]/key[] compile-time indices only (scratch-demotion trap).
__global__ __launch_bounds__(256,5) void k_main(const u16* __restrict__ TXT, const u16* __restrict__ LOC,
                                                const float* __restrict__ ewg, const float* __restrict__ vbuf,
                                                float* __restrict__ bias){
  __shared__ __align__(16) char smem[30592];   // A dbuf 28672 | exchange 4x7424=29696 | ewl 896
  const int tid = threadIdx.x, lane = tid & 63, wv = tid >> 6;
  const int quad = lane >> 4, l16 = lane & 15;
  const int ms = wv >> 1, ns = wv & 1;
  const int lsw = lane ^ ((lane>>3)&3);        // stage-side swizzled source lane
  const int qsw = (quad ^ ((l16>>1)&3)) * 16;  // read-side swizzled slot byte offset

  // group swizzle: groups of 32 cn-tiles x 32 b; last group 29 x 32
  int id = blockIdx.x, b, cnt_;
  if (id < 24576){
    int g = id >> 10, r = id & 1023;
    b = r >> 5;  cnt_ = (g << 5) + (r & 31);
  } else {
    int r = id - 24576;
    b = r / 29;  cnt_ = 768 + r % 29;
  }
  const int cn0 = cnt_ * 64;

  // stage ew early (region disjoint from A dbuf; read only after final K barrier)
  float* ewl = (float*)(smem + 29696);
  if (tid < 224) ewl[tid] = ewg[(size_t)b*224 + tid];

  const f32x4 zero = {0.f,0.f,0.f,0.f};
  f32x4 acc[7][2];
  #pragma unroll
  for (int t=0;t<7;++t){ acc[t][0]=zero; acc[t][1]=zero; }

  const u16* Abase = LOC + (size_t)(b*16)*224*32;
  char* Albd0 = smem;
  char* Albd1 = smem + 14336;

  auto stageA = [&](int kc, char* dst){
    const char* src = (const char*)(Abase + (size_t)kc*224*32);
    #pragma unroll
    for (int j=0;j<4;++j){
      int ch0 = j*256 + wv*64;                 // wave-uniform chunk base
      if (ch0 < 896)
        cp16(dst + (size_t)ch0*16, src + (size_t)(ch0 + lsw)*16);
    }
  };
  auto loadB = [&](int kc)->B2{
    B2 r;
    size_t e = ((size_t)kc*51008 + (size_t)(cn0 + 32*ns + l16))*32 + quad*8;
    r.x = *(const bf16x8*)(TXT + e);
    r.y = *(const bf16x8*)(TXT + e + 16*32);
    return r;
  };
  auto domfma = [&](const char* Ab, B2 bb){
    #pragma unroll
    for (int t=0;t<7;++t){
      bf16x8 af = *(const bf16x8*)(Ab + (size_t)((112*ms + 16*t + l16)*64) + qsw);
      acc[t][0] = __builtin_amdgcn_mfma_f32_16x16x32_bf16(af, bb.x, acc[t][0], 0,0,0);
      acc[t][1] = __builtin_amdgcn_mfma_f32_16x16x32_bf16(af, bb.y, acc[t][1], 0,0,0);
    }
  };

  stageA(0, Albd0);
  B2 bcur = loadB(0);
  __syncthreads();

  for (int kc = 0; kc < 16; ++kc){
    char* cur = (kc & 1) ? Albd1 : Albd0;
    char* nxt = (kc & 1) ? Albd0 : Albd1;
    B2 bnext;
    if (kc < 15){
      stageA(kc+1, nxt);
      bnext = loadB(kc+1);
    }
    domfma(cur, bcur);
    bcur = bnext;
    __syncthreads();
  }

  // ---- epilogue: exchange complementary m-half, then integer-key selection ----
  // region(ns,j2) layout: [col l16][m-local 112+pad4] floats, stride 116 (2-way banks = free)
  {
    char* wr = smem + (size_t)(((ns<<1)|(ms^1))*7424) + l16*464;
    if (ms == 0){
      #pragma unroll
      for (int t=0;t<7;++t) *(f32x4*)(wr + (16*t+4*quad)*4) = acc[t][1];
    } else {
      #pragma unroll
      for (int t=0;t<7;++t) *(f32x4*)(wr + (16*t+4*quad)*4) = acc[t][0];
    }
  }
  __syncthreads();

  f32x4 own[7], oth[7];
  {
    const char* rd = smem + (size_t)(((ns<<1)|ms)*7424) + l16*464;
    #pragma unroll
    for (int t=0;t<7;++t) oth[t] = *(const f32x4*)(rd + (16*t+4*quad)*4);
    if (ms == 0){
      #pragma unroll
      for (int t=0;t<7;++t) own[t] = acc[t][0];
    } else {
      #pragma unroll
      for (int t=0;t<7;++t) own[t] = acc[t][1];
    }
  }

  // ---- build packed integer keys (order-preserving; 2 keys / 32-bit reg) ----
  // real sims |x| <= ~1.01 -> |key| <= ~15550; pad sentinel -16000 below all real.
  const int PKPK = (int)0xC180C180;  // two packed -16000 sentinels
  int kown[7][2], koth[7][2];
  #pragma unroll
  for (int t=0;t<7;++t){
    int a0 = (int)(own[t][0]*15360.0f), a1 = (int)(own[t][1]*15360.0f);
    int a2 = (int)(own[t][2]*15360.0f), a3 = (int)(own[t][3]*15360.0f);
    int b0 = (int)(oth[t][0]*15360.0f), b1 = (int)(oth[t][1]*15360.0f);
    int b2 = (int)(oth[t][2]*15360.0f), b3 = (int)(oth[t][3]*15360.0f);
    kown[t][0] = (a0 & 0xffff) | (a1 << 16);
    kown[t][1] = (a2 & 0xffff) | (a3 << 16);
    koth[t][0] = (b0 & 0xffff) | (b1 << 16);
    koth[t][1] = (b2 & 0xffff) | (b3 << 16);
  }
  // pad slots (m>=196): half-1 t=5 (quad!=0) and all of t=6 of the half-1 array.
  if (ms == 1){
    if (quad != 0){ kown[5][0] = PKPK; kown[5][1] = PKPK; }
    kown[6][0] = PKPK; kown[6][1] = PKPK;
  } else {
    if (quad != 0){ koth[5][0] = PKPK; koth[5][1] = PKPK; }
    koth[6][0] = PKPK; koth[6][1] = PKPK;
  }

  // ---- bracket from t=0..4 (all real; 160 samples/column) ----
  s16x2 vmn = as_s16x2(kown[0][0]), vmx = vmn;
  #pragma unroll
  for (int t=0;t<5;++t){
    #pragma unroll
    for (int i=0;i<2;++i){
      vmn = pkmin2(vmn, as_s16x2(kown[t][i]));  vmx = pkmax2(vmx, as_s16x2(kown[t][i]));
      vmn = pkmin2(vmn, as_s16x2(koth[t][i]));  vmx = pkmax2(vmx, as_s16x2(koth[t][i]));
    }
  }
  int kmn = min((int)vmn.x, (int)vmn.y);
  int kmx = max((int)vmx.x, (int)vmx.y);
  kmn = qmin_i(kmn); kmx = qmax_i(kmx);
  int lo = kmn - 1, hi = kmx + 1;   // cnt(lo)>=160>=50, cnt(hi)<=36<50

  // ---- integer false position (Illinois) on packed counts ----
  float flo = 146.0f, fhi = -50.0f;   // counts-50 at lo/hi (flo is a safe estimate)
  int side = 0;
  bool done = false;

  #pragma unroll 1
  for (int it = 0; it < 14; ++it){
    float fr = flo * __builtin_amdgcn_rcpf(flo - fhi);
    fr = fminf(fmaxf(fr, 0.04f), 0.96f);
    int tm = lo + (int)(fr * (float)(hi - lo));
    tm = (tm <= lo) ? (lo + 1) : ((tm >= hi) ? (hi - 1) : tm);

    s16x2 tmv = as_s16x2((tm & 0xffff) | (tm << 16));
    s16x2 ca = {0,0};
    #pragma unroll
    for (int t=0;t<7;++t){
      ca = ca + ((as_s16x2(kown[t][0]) - tmv) >> 15);
      ca = ca + ((as_s16x2(kown[t][1]) - tmv) >> 15);
      ca = ca + ((as_s16x2(koth[t][0]) - tmv) >> 15);
      ca = ca + ((as_s16x2(koth[t][1]) - tmv) >> 15);
    }
    int clt = -((int)ca.x + (int)ca.y);    // lanes' below-count (pads always below)
    int c = qsum_i(56 - clt);              // column's >=tm count (real only)

    bool ge = (c >= 50);
    if (!done){
      if (ge){ fhi = (side==1)  ? fhi*0.5f : fhi; flo = (float)(c-50); lo = tm; side = 1; }
      else   { flo = (side==-1) ? flo*0.5f : flo; fhi = (float)(c-50); hi = tm; side = -1; }
    }
    done = done || (c == 50) || ((hi - lo) <= 1);
    if (__all(done)) break;
  }
  const s16x2 thrv = as_s16x2((lo & 0xffff) | (lo << 16));

  // ---- final weighted sum (membership by key >= lo; pads self-excluded) ----
  float num = 0.f, den = 0.f;
  #pragma unroll
  for (int t=0;t<7;++t){
    f32x4 eA = *(const f32x4*)(ewl + 112*ms     + 16*t + 4*quad);
    f32x4 eB = *(const f32x4*)(ewl + 112*(ms^1) + 16*t + 4*quad);
    s16x2 d0 = as_s16x2(kown[t][0]) - thrv;
    s16x2 d1 = as_s16x2(kown[t][1]) - thrv;
    s16x2 e0 = as_s16x2(koth[t][0]) - thrv;
    s16x2 e1 = as_s16x2(koth[t][1]) - thrv;
    if (d0.x >= 0){ num = fmaf(own[t][0], eA[0], num); den += eA[0]; }
    if (d0.y >= 0){ num = fmaf(own[t][1], eA[1], num); den += eA[1]; }
    if (d1.x >= 0){ num = fmaf(own[t][2], eA[2], num); den += eA[2]; }
    if (d1.y >= 0){ num = fmaf(own[t][3], eA[3], num); den += eA[3]; }
    if (e0.x >= 0){ num = fmaf(oth[t][0], eB[0], num); den += eB[0]; }
    if (e0.y >= 0){ num = fmaf(oth[t][1], eB[1], num); den += eB[1]; }
    if (e1.x >= 0){ num = fmaf(oth[t][2], eB[2], num); den += eB[2]; }
    if (e1.y >= 0){ num = fmaf(oth[t][3], eB[3], num); den += eB[3]; }
  }
  num = qsum_f(num);
  den = qsum_f(den);

  int cn = cn0 + 32*ns + 16*ms + l16;
  if (quad == 0 && cn < 51000){
    int c = cn/51;
    atomicAdd(bias + (size_t)b*1000 + c, vbuf[cn]*(num/den));
  }
}

// ---------- K7: out = fp32( exp(logit_scale) * bias ) ----------
__global__ void k_out(const float* __restrict__ bias, const float* __restrict__ ls, float* __restrict__ out){
  int i = blockIdx.x*256 + threadIdx.x;
  if (i < 32000){
    float sc = expf(ls[0]);
    out[i] = sc * bias[i];
  }
}

// ---------- launch ----------
extern "C" void kernel_launch(void* const* d_in, const int* in_sizes, int n_in,
                              void* d_out, int out_size, void* d_ws, size_t ws_size,
                              hipStream_t stream) {
  const float* img = (const float*)d_in[0];
  const float* loc = (const float*)d_in[1];
  const float* txt = (const float*)d_in[2];
  const float* ls  = (const float*)d_in[3];
  char* ws = (char*)d_ws;
  float* imgn = (float*)(ws + 0);            //  65536
  float* MT   = (float*)(ws + 65536);        //  2048000
  float* invn = (float*)(ws + 2113536);      //  204032
  float* vbuf = (float*)(ws + 2317568);      //  204032
  float* ewg  = (float*)(ws + 2521600);      //  28672
  float* bias = (float*)(ws + 2550272);      //  128000
  u16*   TXT  = (u16*)  (ws + 2678272);      //  52232192
  u16*   LOC  = (u16*)  (ws + 54910464);     //  7340032

  k_img <<<dim3(32),      dim3(64),  0, stream>>>(img, imgn);
  k_txt <<<dim3(51008),   dim3(64),  0, stream>>>(txt, TXT, invn);
  k_mean<<<dim3(1000),    dim3(256), 0, stream>>>(txt, invn, MT);
  k_v   <<<dim3(1000),    dim3(64),  0, stream>>>(TXT, MT, vbuf);
  k_base<<<dim3(1000),    dim3(64),  0, stream>>>(imgn, MT, bias);
  k_loc <<<dim3(224,32),  dim3(64),  0, stream>>>(loc, imgn, LOC, ewg);
  k_main<<<dim3(25504),   dim3(256), 0, stream>>>(TXT, LOC, ewg, vbuf, bias);
  k_out <<<dim3(125),     dim3(256), 0, stream>>>(bias, ls, (float*)d_out);
}